// Round 15
// baseline (438.230 us; speedup 1.0000x reference)
//
#include <hip/hip_runtime.h>
#include <math.h>

typedef __attribute__((ext_vector_type(4))) float f32x4;
typedef __attribute__((ext_vector_type(8))) __bf16 bf16x8;

#define MFMA_BF16(a, b, c) __builtin_amdgcn_mfma_f32_16x16x32_bf16((a), (b), (c), 0, 0, 0)

static __device__ __forceinline__ unsigned short f2b(float f) {
  unsigned int u = __float_as_uint(f);
  return (unsigned short)((u + 0x7FFFu + ((u >> 16) & 1u)) >> 16);
}
static __device__ __forceinline__ float b2f(unsigned short h) {
  return __uint_as_float(((unsigned int)h) << 16);
}
static __device__ __forceinline__ unsigned short bcvt(float f) {
  __bf16 h = (__bf16)f;
  return __builtin_bit_cast(unsigned short, h);
}

static __device__ __forceinline__ void gll16(const void* g, void* l) {
  __builtin_amdgcn_global_load_lds((const __attribute__((address_space(1))) void*)g,
                                   (__attribute__((address_space(3))) void*)l, 16, 0, 0);
}

// ---------------------------------------------------------------------------
// Segmented multi-tensor fp32->bf16 (one launch for all plain weight converts)
// ---------------------------------------------------------------------------
struct CvtArgs {
  const float* src[12];
  unsigned short* dst[12];
  int start[12];
};
__global__ __launch_bounds__(256) void f2b_multi(CvtArgs a) {
  const int bid = blockIdx.x;
  int s = 11;
#pragma unroll
  for (int i = 11; i >= 1; --i)
    if (bid < a.start[i]) s = i - 1;
  const size_t i4 = (size_t)(bid - a.start[s]) * 256 + threadIdx.x;
  const float4 v = *(const float4*)(a.src[s] + i4 * 4);
  ushort4 o;
  o.x = f2b(v.x); o.y = f2b(v.y); o.z = f2b(v.z); o.w = f2b(v.w);
  *(ushort4*)(a.dst[s] + i4 * 4) = o;
}

// fp32 -> bf16 with ff1 row permutation: a-row r -> 32*(r/16)+(r%16),
// g-row 4096+r -> 32*(r/16)+16+(r%16). One block per source row.
__global__ __launch_bounds__(256) void f2bperm_kernel(const float* __restrict__ src,
                                                      unsigned short* __restrict__ dst) {
  const int r = blockIdx.x;
  const int rr = r & 4095;
  const int dr = ((rr >> 4) << 5) | ((r >> 12) << 4) | (rr & 15);
  const int c = threadIdx.x * 4;
  const float4 v = *(const float4*)(src + (size_t)r * 1024 + c);
  ushort4 o;
  o.x = f2b(v.x); o.y = f2b(v.y); o.z = f2b(v.z); o.w = f2b(v.w);
  *(ushort4*)(dst + (size_t)dr * 1024 + c) = o;
}

// SiLU(x) then bf16
__global__ __launch_bounds__(256) void silu_kernel(const float* __restrict__ src,
                                                   unsigned short* __restrict__ dst, int n) {
  const int i = (blockIdx.x * 256 + threadIdx.x) * 4;
  if (i >= n) return;
  const float4 v = *(const float4*)(src + i);
  ushort4 o;
  o.x = f2b(v.x / (1.f + expf(-v.x)));
  o.y = f2b(v.y / (1.f + expf(-v.y)));
  o.z = f2b(v.z / (1.f + expf(-v.z)));
  o.w = f2b(v.w / (1.f + expf(-v.w)));
  *(ushort4*)(dst + i) = o;
}

// ---------------------------------------------------------------------------
// eq-LN (groups of 256) + optional AdaLN scale/shift (bf16 ss, stride 4096)
// ---------------------------------------------------------------------------
template <int ADA>
__global__ __launch_bounds__(256) void eqln_kernel(const float* __restrict__ x,
                                                   const unsigned short* __restrict__ ss,
                                                   unsigned short* __restrict__ outp) {
  const int n = blockIdx.x;
  const int tid = threadIdx.x;
  const int g = tid >> 6, lane = tid & 63;
  const size_t base = (size_t)n * 1024 + g * 256 + lane * 4;
  const float4 v = *(const float4*)(x + base);
  float s = v.x + v.y + v.z + v.w;
  float s2 = v.x * v.x + v.y * v.y + v.z * v.z + v.w * v.w;
#pragma unroll
  for (int m = 1; m < 64; m <<= 1) {
    s += __shfl_xor(s, m, 64);
    s2 += __shfl_xor(s2, m, 64);
  }
  const float mu = s * (1.f / 256.f);
  const float var = s2 * (1.f / 256.f) - mu * mu;
  const float rs = rsqrtf(var + 1e-5f);
  float o0 = (v.x - mu) * rs, o1 = (v.y - mu) * rs, o2 = (v.z - mu) * rs, o3 = (v.w - mu) * rs;
  if (ADA) {
    const size_t sb = (size_t)n * 4096 + g * 256 + lane * 4;
    const ushort4 scv = *(const ushort4*)(ss + sb);
    const ushort4 shv = *(const ushort4*)(ss + sb + 1024);
    o0 = o0 * (1.f + b2f(scv.x)) + b2f(shv.x);
    o1 = o1 * (1.f + b2f(scv.y)) + b2f(shv.y);
    o2 = o2 * (1.f + b2f(scv.z)) + b2f(shv.z);
    o3 = o3 * (1.f + b2f(scv.w)) + b2f(shv.w);
  }
  ushort4 ov;
  ov.x = f2b(o0); ov.y = f2b(o1); ov.z = f2b(o2); ov.w = f2b(o3);
  *(ushort4*)(outp + base) = ov;
}

// ---------------------------------------------------------------------------
// V transpose: v (rows x ld, bf16, head h cols) -> vt (B, H, 64, T)
// ---------------------------------------------------------------------------
__global__ __launch_bounds__(256) void vtrans_kernel(const unsigned short* __restrict__ v,
                                                     unsigned short* __restrict__ vt, int T,
                                                     int ld) {
  const int t0 = blockIdx.x * 64, h = blockIdx.y, b = blockIdx.z;
  __shared__ unsigned short tile[64][65];
  const int tid = threadIdx.x;
#pragma unroll
  for (int rr = 0; rr < 2; ++rr) {
    const int tok = rr * 32 + (tid >> 3);
    const int d8 = (tid & 7) * 8;
    const uint4 x = *(const uint4*)(v + (size_t)(b * T + t0 + tok) * ld + h * 64 + d8);
    const unsigned int* xs = (const unsigned int*)&x;
#pragma unroll
    for (int j = 0; j < 4; ++j) {
      tile[d8 + 2 * j][tok] = (unsigned short)(xs[j] & 0xffffu);
      tile[d8 + 2 * j + 1][tok] = (unsigned short)(xs[j] >> 16);
    }
  }
  __syncthreads();
#pragma unroll
  for (int rr = 0; rr < 2; ++rr) {
    const int d = rr * 32 + (tid >> 3);
    const int t8 = (tid & 7) * 8;
    uint4 ov;
    unsigned int* ou = (unsigned int*)&ov;
#pragma unroll
    for (int j = 0; j < 4; ++j)
      ou[j] = (unsigned int)tile[d][t8 + 2 * j] | ((unsigned int)tile[d][t8 + 2 * j + 1] << 16);
    *(uint4*)(vt + ((size_t)((b * 16 + h) * 64 + d)) * T + t0 + t8) = ov;
  }
}

// ---------------------------------------------------------------------------
// GEMM (m97 structure): single-buffered LDS, stage -> barrier -> MFMA ->
// barrier; latency hidden by co-resident blocks (launch_bounds(256,4)).
// ---------------------------------------------------------------------------
template <int BM, int BIAS, int RES, int OUTMODE>
__global__ __launch_bounds__(256, 4) void gemm_nt(const unsigned short* __restrict__ A,
                                                  const unsigned short* __restrict__ Bw,
                                                  const float* __restrict__ bias,
                                                  const float* res, void* Cout,
                                                  int M, int N, int K) {
  constexpr int MB = BM / 32;
  __shared__ unsigned short As[BM * 64];
  __shared__ unsigned short Bs[128 * 64];
  const int m0 = blockIdx.x * BM, n0 = blockIdx.y * 128;
  const int tid = threadIdx.x, lane = tid & 63;
  const int wr = (tid >> 7) & 1, wc = (tid >> 6) & 1;
  const int lr = lane & 15, ls = lane >> 4;

  const f32x4 fz = {0.f, 0.f, 0.f, 0.f};
  f32x4 acc[MB][4];
#pragma unroll
  for (int m = 0; m < MB; ++m)
#pragma unroll
    for (int n = 0; n < 4; ++n) acc[m][n] = fz;

  for (int k0 = 0; k0 < K; k0 += 64) {
#pragma unroll
    for (int it = 0; it < BM / 32; ++it) {
      const int u = it * 256 + tid;
      const int row = u >> 3, gs = (u & 7) ^ (row & 7);
      gll16(A + (size_t)(m0 + row) * K + k0 + gs * 8, As + u * 8);
    }
#pragma unroll
    for (int it = 0; it < 4; ++it) {
      const int u = it * 256 + tid;
      const int row = u >> 3, gs = (u & 7) ^ (row & 7);
      gll16(Bw + (size_t)(n0 + row) * K + k0 + gs * 8, Bs + u * 8);
    }
    __syncthreads();
#pragma unroll
    for (int kk = 0; kk < 2; ++kk) {
      bf16x8 af[MB], bfr[4];
#pragma unroll
      for (int m = 0; m < MB; ++m) {
        const int row = wr * (BM / 2) + m * 16 + lr;
        const int slot = (kk * 4 + ls) ^ (row & 7);
        af[m] = *(const bf16x8*)(As + row * 64 + slot * 8);
      }
#pragma unroll
      for (int n = 0; n < 4; ++n) {
        const int col = wc * 64 + n * 16 + lr;
        const int slot = (kk * 4 + ls) ^ (col & 7);
        bfr[n] = *(const bf16x8*)(Bs + col * 64 + slot * 8);
      }
#pragma unroll
      for (int m = 0; m < MB; ++m)
#pragma unroll
        for (int n = 0; n < 4; ++n) acc[m][n] = MFMA_BF16(af[m], bfr[n], acc[m][n]);
    }
    __syncthreads();
  }

  if (OUTMODE == 2) {
    const int pn0 = n0 + wc * 64;
#pragma unroll
    for (int m = 0; m < MB; ++m) {
#pragma unroll
      for (int j = 0; j < 2; ++j) {
        const int ocol = (pn0 >> 1) + j * 16 + lr;
        const float ba = bias[ocol];
        const float bg = bias[(N >> 1) + ocol];
#pragma unroll
        for (int r = 0; r < 4; ++r) {
          const int row = m0 + wr * (BM / 2) + m * 16 + ls * 4 + r;
          const float a = acc[m][2 * j][r] + ba;
          const float g = acc[m][2 * j + 1][r] + bg;
          const float gl = 0.5f * g * (1.f + erff(g * 0.70710678118654752f));
          ((unsigned short*)Cout)[(size_t)row * (N >> 1) + ocol] = f2b(a * gl);
        }
      }
    }
    return;
  }
#pragma unroll
  for (int m = 0; m < MB; ++m) {
#pragma unroll
    for (int n = 0; n < 4; ++n) {
      const int col = n0 + wc * 64 + n * 16 + lr;
      float bv = 0.f;
      if (BIAS) bv = bias[col];
#pragma unroll
      for (int r = 0; r < 4; ++r) {
        const int row = m0 + wr * (BM / 2) + m * 16 + ls * 4 + r;
        float v = acc[m][n][r] + bv;
        if (RES) v += res[(size_t)row * N + col];
        if (OUTMODE == 1)
          ((unsigned short*)Cout)[(size_t)row * N + col] = f2b(v);
        else
          ((float*)Cout)[(size_t)row * N + col] = v;
      }
    }
  }
}

// ---------------------------------------------------------------------------
// Flash attention v9: single-buffered K+V LDS, KVBLK=64, 24KB LDS -> ~6
// blocks/CU (m97 pattern: stage -> barrier -> compute -> barrier; drains
// covered by co-resident blocks). No-max softmax, ones-MFMA row sum,
// XCD-bijective swizzle, setprio.
// ---------------------------------------------------------------------------
template <int RELB>
__global__ __launch_bounds__(256) void attn_kernel(const unsigned short* __restrict__ q,
                                                   const unsigned short* __restrict__ k,
                                                   const unsigned short* __restrict__ vt,
                                                   const float* __restrict__ rel,
                                                   unsigned short* __restrict__ outp,
                                                   int ldq, int ldk) {
  const int lin = blockIdx.x + (blockIdx.y << 4) + (blockIdx.z << 8);
  const int xcd = lin & 7, s = lin >> 3;
  const int g = (xcd << 3) + (s >> 4);
  const int qb = s & 15;
  const int h = g & 15, b = g >> 4;
  const int tid = threadIdx.x;
  const int wid = tid >> 6, lane = tid & 63;
  const int lr = lane & 15, ls = lane >> 4;
  const int q0 = (qb << 6) + (wid << 4);
  const float L2E = 1.44269504088896340736f;

  __shared__ unsigned short Ks[64 * 64];      // K tile [kv-row][d], slot-swizzled
  __shared__ unsigned short Vs[64 * 64];      // V tile [d-row][kv], chunk-swizzled
  __shared__ unsigned short plds[4][16][64];  // per-wave P strip
  __shared__ float tbl[66];

  if (RELB && tid < 65) tbl[tid] = rel[h * 65 + tid] * L2E;

  bf16x8 qa0, qa1;
  {
    const unsigned short* qp = q + (size_t)(b * 1024 + q0 + lr) * ldq + h * 64 + ls * 8;
    const bf16x8 t0 = *(const bf16x8*)qp;
    const bf16x8 t1 = *(const bf16x8*)(qp + 32);
    const float sc = 0.125f * L2E;
#pragma unroll
    for (int j = 0; j < 8; ++j) {
      qa0[j] = (__bf16)((float)t0[j] * sc);
      qa1[j] = (__bf16)((float)t1[j] * sc);
    }
  }
  bf16x8 ones;
#pragma unroll
  for (int j = 0; j < 8; ++j) ones[j] = (__bf16)1.0f;

  const f32x4 fz = {0.f, 0.f, 0.f, 0.f};
  f32x4 oacc[4];
#pragma unroll
  for (int d = 0; d < 4; ++d) oacc[d] = fz;
  f32x4 lacc = fz;

  const unsigned short* kbp = k + (size_t)(b * 1024) * ldk + h * 64;
  const unsigned short* vbp = vt + (size_t)((b * 16 + h) * 64) * 1024;

  // stage K tile: 64 rows x 64 d; 8 chunk-slots/row, XOR-swizzled
  auto stageK = [&](int kv0) {
#pragma unroll
    for (int it = 0; it < 2; ++it) {
      const int u = it * 256 + tid;
      const int row = u >> 3, gs = (u & 7) ^ (row & 7);
      gll16(kbp + (size_t)(kv0 + row) * ldk + gs * 8, Ks + u * 8);
    }
  };
  // stage V tile: 64 d-rows x 64 kv; 8 chunk-slots/row, XOR-swizzled
  auto stageV = [&](int kv0) {
#pragma unroll
    for (int it = 0; it < 2; ++it) {
      const int u = it * 256 + tid;
      const int row = u >> 3, ch = u & 7;
      const int gs = ch ^ (row & 7);
      gll16(vbp + (size_t)row * 1024 + kv0 + gs * 8, Vs + u * 8);
    }
  };

  stageK(0);
  stageV(0);

  for (int t = 0; t < 16; ++t) {
    const int kvs = t << 6;
    __syncthreads();  // staged tile visible (also covers tbl on first iter)
    // QK^T from LDS
    f32x4 sc4[4];
    __builtin_amdgcn_s_setprio(1);
#pragma unroll
    for (int nn = 0; nn < 4; ++nn) {
      const int row = nn * 16 + lr;
      const int s0 = ls ^ (row & 7), s1 = (4 + ls) ^ (row & 7);
      const bf16x8 kb0 = *(const bf16x8*)(Ks + row * 64 + s0 * 8);
      const bf16x8 kb1 = *(const bf16x8*)(Ks + row * 64 + s1 * 8);
      f32x4 acc = fz;
      acc = MFMA_BF16(qa0, kb0, acc);
      acc = MFMA_BF16(qa1, kb1, acc);
      sc4[nn] = acc;
    }
    __builtin_amdgcn_s_setprio(0);
    // rel bias (Toeplitz fast path)
    float cb = 0.f;
    bool vary = false;
    if (RELB) {
      if (kvs + 95 <= q0) {
        cb = tbl[64];
      } else if (kvs >= q0 + 47) {
        cb = tbl[0];
      } else {
        vary = true;
      }
    }
    // P = exp2(min(s+bias, 60)) into swizzled per-wave strip (m = 0)
    if (vary) {
      const int bd = q0 + ls * 4 - (kvs + lr);
#pragma unroll
      for (int nn = 0; nn < 4; ++nn)
#pragma unroll
        for (int r = 0; r < 4; ++r) {
          int dl = bd + r - nn * 16;
          dl = dl < -32 ? -32 : (dl > 32 ? 32 : dl);
          const float p = __builtin_amdgcn_exp2f(fminf(sc4[nn][r] + tbl[dl + 32], 60.f));
          const int qq = ls * 4 + r;
          const int colw = ((((nn << 1) + (lr >> 3)) ^ (qq & 7)) << 3) + (lr & 7);
          plds[wid][qq][colw] = bcvt(p);
        }
    } else {
#pragma unroll
      for (int nn = 0; nn < 4; ++nn)
#pragma unroll
        for (int r = 0; r < 4; ++r) {
          const float p = __builtin_amdgcn_exp2f(fminf(sc4[nn][r] + cb, 60.f));
          const int qq = ls * 4 + r;
          const int colw = ((((nn << 1) + (lr >> 3)) ^ (qq & 7)) << 3) + (lr & 7);
          plds[wid][qq][colw] = bcvt(p);
        }
    }
    asm volatile("" ::: "memory");
    // PV + ones-column row sum (V from LDS, chunk-swizzled)
    const bf16x8 pa0 = *(const bf16x8*)&plds[wid][lr][((ls ^ (lr & 7)) << 3)];
    const bf16x8 pa1 = *(const bf16x8*)&plds[wid][lr][(((4 + ls) ^ (lr & 7)) << 3)];
    __builtin_amdgcn_s_setprio(1);
    lacc = MFMA_BF16(pa0, ones, lacc);
    lacc = MFMA_BF16(pa1, ones, lacc);
#pragma unroll
    for (int d = 0; d < 4; ++d) {
      const int rr = d * 16 + lr;
      const int c0s = ls ^ (rr & 7);
      const int c1s = (4 + ls) ^ (rr & 7);
      const bf16x8 vb0 = *(const bf16x8*)(Vs + rr * 64 + c0s * 8);
      const bf16x8 vb1 = *(const bf16x8*)(Vs + rr * 64 + c1s * 8);
      oacc[d] = MFMA_BF16(pa0, vb0, oacc[d]);
      oacc[d] = MFMA_BF16(pa1, vb1, oacc[d]);
    }
    __builtin_amdgcn_s_setprio(0);
    __syncthreads();  // all waves done reading Ks/Vs
    if (t + 1 < 16) {
      stageK(kvs + 64);
      stageV(kvs + 64);
    }
  }

  float rinv[4];
#pragma unroll
  for (int r = 0; r < 4; ++r) rinv[r] = 1.0f / lacc[r];
#pragma unroll
  for (int d = 0; d < 4; ++d)
#pragma unroll
    for (int r = 0; r < 4; ++r) {
      const float v = oacc[d][r] * rinv[r];
      outp[(size_t)(b * 1024 + q0 + ls * 4 + r) * 1024 + h * 64 + d * 16 + lr] = bcvt(v);
    }
}

// ---------------------------------------------------------------------------
extern "C" void kernel_launch(void* const* d_in, const int* in_sizes, int n_in,
                              void* d_out, int out_size, void* d_ws, size_t ws_size,
                              hipStream_t stream) {
  (void)in_sizes; (void)n_in; (void)out_size; (void)ws_size;
  const float* hs = (const float*)d_in[0];
  const float* enc = (const float*)d_in[1];
  const float* temb = (const float*)d_in[2];
  const float* wada1 = (const float*)d_in[3];
  const float* bada1 = (const float*)d_in[4];
  const float* wada2 = (const float*)d_in[5];
  const float* bada2 = (const float*)d_in[6];
  const float* wq1 = (const float*)d_in[7];
  const float* wk1 = (const float*)d_in[8];
  const float* wv1 = (const float*)d_in[9];
  const float* wo1 = (const float*)d_in[10];
  const float* bo1 = (const float*)d_in[11];
  const float* rel = (const float*)d_in[12];
  const float* wq2 = (const float*)d_in[13];
  const float* wk2 = (const float*)d_in[14];
  const float* wv2 = (const float*)d_in[15];
  const float* wo2 = (const float*)d_in[16];
  const float* bo2 = (const float*)d_in[17];
  const float* wff1 = (const float*)d_in[18];
  const float* bff1 = (const float*)d_in[19];
  const float* wff2 = (const float*)d_in[20];
  const float* bff2 = (const float*)d_in[21];
  float* out = (float*)d_out;

  char* ws = (char*)d_ws;
  const size_t MB = 1024ull * 1024ull;
  unsigned short* wb_ada = (unsigned short*)(ws + 0 * MB);     // 8MB (ada1|ada2 concat)
  unsigned short* wb_q1 = (unsigned short*)(ws + 8 * MB);      // qkv1 contiguous 6MB
  unsigned short* wb_k1 = (unsigned short*)(ws + 10 * MB);
  unsigned short* wb_v1 = (unsigned short*)(ws + 12 * MB);
  unsigned short* wb_o1 = (unsigned short*)(ws + 14 * MB);
  unsigned short* wb_q2 = (unsigned short*)(ws + 16 * MB);
  unsigned short* wb_k2 = (unsigned short*)(ws + 18 * MB);     // kv2 contiguous 4MB
  unsigned short* wb_v2 = (unsigned short*)(ws + 20 * MB);
  unsigned short* wb_o2 = (unsigned short*)(ws + 22 * MB);
  unsigned short* wb_ff1 = (unsigned short*)(ws + 24 * MB);    // 16MB (permuted)
  unsigned short* wb_ff2 = (unsigned short*)(ws + 40 * MB);    // 8MB
  unsigned short* silu_t = (unsigned short*)(ws + 48 * MB);    // 8MB
  unsigned short* enc_b = (unsigned short*)(ws + 56 * MB);     // 8MB
  unsigned short* ssb = (unsigned short*)(ws + 64 * MB);       // 32MB bf16 (stage 1/2)
  unsigned short* ffin = (unsigned short*)(ws + 64 * MB);      // 32MB (stage 3, aliases ssb)
  float* bias_cat = (float*)(ws + 96 * MB);                    // 16KB (bada1|bada2)
  unsigned short* x1b = (unsigned short*)(ws + 97 * MB);       // 8MB
  unsigned short* qkvb = (unsigned short*)(ws + 105 * MB);     // 24MB (stage 1)
  unsigned short* qb = (unsigned short*)(ws + 105 * MB);       // 8MB (stage 2)
  unsigned short* kvb = (unsigned short*)(ws + 113 * MB);      // 16MB (stage 2)
  unsigned short* vtb = (unsigned short*)(ws + 129 * MB);      // 8MB
  unsigned short* aob = (unsigned short*)(ws + 137 * MB);      // 8MB, ends 145MB

  const int Nrow = 4096;

  // ---- converts (single launch) + bias concat (d2d, graph-safe) ----
  {
    CvtArgs a;
    const float* srcs[12] = {wada1, wada2, wq1, wk1, wv1, wo1, wq2, wk2, wv2, wo2, wff2, enc};
    unsigned short* dsts[12] = {wb_ada, wb_ada + 2048 * 1024, wb_q1, wb_k1, wb_v1, wb_o1,
                                wb_q2, wb_k2, wb_v2, wb_o2, wb_ff2, enc_b};
    const int blks[12] = {2048, 2048, 1024, 1024, 1024, 1024, 1024, 1024, 1024, 1024, 4096, 4096};
    int acc = 0;
    for (int i = 0; i < 12; ++i) { a.src[i] = srcs[i]; a.dst[i] = dsts[i]; a.start[i] = acc; acc += blks[i]; }
    f2b_multi<<<acc, 256, 0, stream>>>(a);
  }
  (void)hipMemcpyAsync(bias_cat, bada1, 2048 * sizeof(float), hipMemcpyDeviceToDevice, stream);
  (void)hipMemcpyAsync(bias_cat + 2048, bada2, 2048 * sizeof(float), hipMemcpyDeviceToDevice, stream);
  f2bperm_kernel<<<8192, 256, 0, stream>>>(wff1, wb_ff1);
  silu_kernel<<<4096, 256, 0, stream>>>(temb, silu_t, 4096 * 1024);

  // ---- batched AdaLN GEMM: ss(4096x4096 bf16) = silu_t @ [wada1|wada2]^T + b ----
  gemm_nt<128, 1, 0, 1><<<dim3(32, 32), 256, 0, stream>>>(silu_t, wb_ada, bias_cat, nullptr, ssb, Nrow, 4096, 1024);

  // ---- stage 1: AdaLN + self-attn + residual ----
  eqln_kernel<1><<<4096, 256, 0, stream>>>(hs, ssb, x1b);
  gemm_nt<128, 0, 0, 1><<<dim3(32, 24), 256, 0, stream>>>(x1b, wb_q1, nullptr, nullptr, qkvb, Nrow, 3072, 1024);
  vtrans_kernel<<<dim3(16, 16, 4), 256, 0, stream>>>(qkvb + 2048, vtb, 1024, 3072);
  attn_kernel<1><<<dim3(16, 16, 4), 256, 0, stream>>>(qkvb, qkvb + 1024, vtb, rel, aob, 3072, 3072);
  gemm_nt<64, 1, 1, 0><<<dim3(64, 8), 256, 0, stream>>>(aob, wb_o1, bo1, hs, out, Nrow, 1024, 1024);

  // ---- stage 2: AdaLN + cross-attn + residual ----
  eqln_kernel<1><<<4096, 256, 0, stream>>>(out, ssb + 2048, x1b);
  gemm_nt<64, 0, 0, 1><<<dim3(64, 8), 256, 0, stream>>>(x1b, wb_q2, nullptr, nullptr, qb, Nrow, 1024, 1024);
  gemm_nt<128, 0, 0, 1><<<dim3(32, 16), 256, 0, stream>>>(enc_b, wb_k2, nullptr, nullptr, kvb, Nrow, 2048, 1024);
  vtrans_kernel<<<dim3(16, 16, 4), 256, 0, stream>>>(kvb + 1024, vtb, 1024, 2048);
  attn_kernel<0><<<dim3(16, 16, 4), 256, 0, stream>>>(qb, kvb, vtb, nullptr, aob, 1024, 2048);
  gemm_nt<64, 1, 1, 0><<<dim3(64, 8), 256, 0, stream>>>(aob, wb_o2, bo2, out, out, Nrow, 1024, 1024);

  // ---- stage 3: eq-LN + fused GEGLU FFN + residual ----
  eqln_kernel<0><<<4096, 256, 0, stream>>>(out, nullptr, x1b);
  gemm_nt<128, 1, 0, 2><<<dim3(32, 64), 256, 0, stream>>>(x1b, wb_ff1, bff1, nullptr, ffin, Nrow, 8192, 1024);
  gemm_nt<64, 1, 1, 0><<<dim3(64, 8), 256, 0, stream>>>(ffin, wb_ff2, bff2, out, out, Nrow, 1024, 4096);
}

// Round 16
// 427.375 us; speedup vs baseline: 1.0254x; 1.0254x over previous
//
#include <hip/hip_runtime.h>
#include <math.h>

typedef __attribute__((ext_vector_type(4))) float f32x4;
typedef __attribute__((ext_vector_type(8))) __bf16 bf16x8;

#define MFMA_BF16(a, b, c) __builtin_amdgcn_mfma_f32_16x16x32_bf16((a), (b), (c), 0, 0, 0)

static __device__ __forceinline__ unsigned short f2b(float f) {
  unsigned int u = __float_as_uint(f);
  return (unsigned short)((u + 0x7FFFu + ((u >> 16) & 1u)) >> 16);
}
static __device__ __forceinline__ float b2f(unsigned short h) {
  return __uint_as_float(((unsigned int)h) << 16);
}
static __device__ __forceinline__ unsigned short bcvt(float f) {
  __bf16 h = (__bf16)f;
  return __builtin_bit_cast(unsigned short, h);
}

static __device__ __forceinline__ void gll16(const void* g, void* l) {
  __builtin_amdgcn_global_load_lds((const __attribute__((address_space(1))) void*)g,
                                   (__attribute__((address_space(3))) void*)l, 16, 0, 0);
}

// ---------------------------------------------------------------------------
// Segmented multi-tensor fp32->bf16 (one launch for all plain weight converts)
// ---------------------------------------------------------------------------
struct CvtArgs {
  const float* src[12];
  unsigned short* dst[12];
  int start[12];
};
__global__ __launch_bounds__(256) void f2b_multi(CvtArgs a) {
  const int bid = blockIdx.x;
  int s = 11;
#pragma unroll
  for (int i = 11; i >= 1; --i)
    if (bid < a.start[i]) s = i - 1;
  const size_t i4 = (size_t)(bid - a.start[s]) * 256 + threadIdx.x;
  const float4 v = *(const float4*)(a.src[s] + i4 * 4);
  ushort4 o;
  o.x = f2b(v.x); o.y = f2b(v.y); o.z = f2b(v.z); o.w = f2b(v.w);
  *(ushort4*)(a.dst[s] + i4 * 4) = o;
}

// fp32 -> bf16 with ff1 row permutation: a-row r -> 32*(r/16)+(r%16),
// g-row 4096+r -> 32*(r/16)+16+(r%16). One block per source row.
__global__ __launch_bounds__(256) void f2bperm_kernel(const float* __restrict__ src,
                                                      unsigned short* __restrict__ dst) {
  const int r = blockIdx.x;
  const int rr = r & 4095;
  const int dr = ((rr >> 4) << 5) | ((r >> 12) << 4) | (rr & 15);
  const int c = threadIdx.x * 4;
  const float4 v = *(const float4*)(src + (size_t)r * 1024 + c);
  ushort4 o;
  o.x = f2b(v.x); o.y = f2b(v.y); o.z = f2b(v.z); o.w = f2b(v.w);
  *(ushort4*)(dst + (size_t)dr * 1024 + c) = o;
}

// SiLU(x) then bf16
__global__ __launch_bounds__(256) void silu_kernel(const float* __restrict__ src,
                                                   unsigned short* __restrict__ dst, int n) {
  const int i = (blockIdx.x * 256 + threadIdx.x) * 4;
  if (i >= n) return;
  const float4 v = *(const float4*)(src + i);
  ushort4 o;
  o.x = f2b(v.x / (1.f + expf(-v.x)));
  o.y = f2b(v.y / (1.f + expf(-v.y)));
  o.z = f2b(v.z / (1.f + expf(-v.z)));
  o.w = f2b(v.w / (1.f + expf(-v.w)));
  *(ushort4*)(dst + i) = o;
}

// ---------------------------------------------------------------------------
// eq-LN (groups of 256) + optional AdaLN scale/shift (bf16 ss, stride 4096)
// ---------------------------------------------------------------------------
template <int ADA>
__global__ __launch_bounds__(256) void eqln_kernel(const float* __restrict__ x,
                                                   const unsigned short* __restrict__ ss,
                                                   unsigned short* __restrict__ outp) {
  const int n = blockIdx.x;
  const int tid = threadIdx.x;
  const int g = tid >> 6, lane = tid & 63;
  const size_t base = (size_t)n * 1024 + g * 256 + lane * 4;
  const float4 v = *(const float4*)(x + base);
  float s = v.x + v.y + v.z + v.w;
  float s2 = v.x * v.x + v.y * v.y + v.z * v.z + v.w * v.w;
#pragma unroll
  for (int m = 1; m < 64; m <<= 1) {
    s += __shfl_xor(s, m, 64);
    s2 += __shfl_xor(s2, m, 64);
  }
  const float mu = s * (1.f / 256.f);
  const float var = s2 * (1.f / 256.f) - mu * mu;
  const float rs = rsqrtf(var + 1e-5f);
  float o0 = (v.x - mu) * rs, o1 = (v.y - mu) * rs, o2 = (v.z - mu) * rs, o3 = (v.w - mu) * rs;
  if (ADA) {
    const size_t sb = (size_t)n * 4096 + g * 256 + lane * 4;
    const ushort4 scv = *(const ushort4*)(ss + sb);
    const ushort4 shv = *(const ushort4*)(ss + sb + 1024);
    o0 = o0 * (1.f + b2f(scv.x)) + b2f(shv.x);
    o1 = o1 * (1.f + b2f(scv.y)) + b2f(shv.y);
    o2 = o2 * (1.f + b2f(scv.z)) + b2f(shv.z);
    o3 = o3 * (1.f + b2f(scv.w)) + b2f(shv.w);
  }
  ushort4 ov;
  ov.x = f2b(o0); ov.y = f2b(o1); ov.z = f2b(o2); ov.w = f2b(o3);
  *(ushort4*)(outp + base) = ov;
}

// ---------------------------------------------------------------------------
// V transpose: v (rows x ld, bf16, head h cols) -> vt (B, H, 64, T)
// ---------------------------------------------------------------------------
__global__ __launch_bounds__(256) void vtrans_kernel(const unsigned short* __restrict__ v,
                                                     unsigned short* __restrict__ vt, int T,
                                                     int ld) {
  const int t0 = blockIdx.x * 64, h = blockIdx.y, b = blockIdx.z;
  __shared__ unsigned short tile[64][65];
  const int tid = threadIdx.x;
#pragma unroll
  for (int rr = 0; rr < 2; ++rr) {
    const int tok = rr * 32 + (tid >> 3);
    const int d8 = (tid & 7) * 8;
    const uint4 x = *(const uint4*)(v + (size_t)(b * T + t0 + tok) * ld + h * 64 + d8);
    const unsigned int* xs = (const unsigned int*)&x;
#pragma unroll
    for (int j = 0; j < 4; ++j) {
      tile[d8 + 2 * j][tok] = (unsigned short)(xs[j] & 0xffffu);
      tile[d8 + 2 * j + 1][tok] = (unsigned short)(xs[j] >> 16);
    }
  }
  __syncthreads();
#pragma unroll
  for (int rr = 0; rr < 2; ++rr) {
    const int d = rr * 32 + (tid >> 3);
    const int t8 = (tid & 7) * 8;
    uint4 ov;
    unsigned int* ou = (unsigned int*)&ov;
#pragma unroll
    for (int j = 0; j < 4; ++j)
      ou[j] = (unsigned int)tile[d][t8 + 2 * j] | ((unsigned int)tile[d][t8 + 2 * j + 1] << 16);
    *(uint4*)(vt + ((size_t)((b * 16 + h) * 64 + d)) * T + t0 + t8) = ov;
  }
}

// ---------------------------------------------------------------------------
// GEMM (m97 structure): single-buffered LDS, stage -> barrier -> MFMA ->
// barrier; latency hidden by co-resident blocks (launch_bounds(256,4)).
// ---------------------------------------------------------------------------
template <int BM, int BIAS, int RES, int OUTMODE>
__global__ __launch_bounds__(256, 4) void gemm_nt(const unsigned short* __restrict__ A,
                                                  const unsigned short* __restrict__ Bw,
                                                  const float* __restrict__ bias,
                                                  const float* res, void* Cout,
                                                  int M, int N, int K) {
  constexpr int MB = BM / 32;
  __shared__ unsigned short As[BM * 64];
  __shared__ unsigned short Bs[128 * 64];
  const int m0 = blockIdx.x * BM, n0 = blockIdx.y * 128;
  const int tid = threadIdx.x, lane = tid & 63;
  const int wr = (tid >> 7) & 1, wc = (tid >> 6) & 1;
  const int lr = lane & 15, ls = lane >> 4;

  const f32x4 fz = {0.f, 0.f, 0.f, 0.f};
  f32x4 acc[MB][4];
#pragma unroll
  for (int m = 0; m < MB; ++m)
#pragma unroll
    for (int n = 0; n < 4; ++n) acc[m][n] = fz;

  for (int k0 = 0; k0 < K; k0 += 64) {
#pragma unroll
    for (int it = 0; it < BM / 32; ++it) {
      const int u = it * 256 + tid;
      const int row = u >> 3, gs = (u & 7) ^ (row & 7);
      gll16(A + (size_t)(m0 + row) * K + k0 + gs * 8, As + u * 8);
    }
#pragma unroll
    for (int it = 0; it < 4; ++it) {
      const int u = it * 256 + tid;
      const int row = u >> 3, gs = (u & 7) ^ (row & 7);
      gll16(Bw + (size_t)(n0 + row) * K + k0 + gs * 8, Bs + u * 8);
    }
    __syncthreads();
#pragma unroll
    for (int kk = 0; kk < 2; ++kk) {
      bf16x8 af[MB], bfr[4];
#pragma unroll
      for (int m = 0; m < MB; ++m) {
        const int row = wr * (BM / 2) + m * 16 + lr;
        const int slot = (kk * 4 + ls) ^ (row & 7);
        af[m] = *(const bf16x8*)(As + row * 64 + slot * 8);
      }
#pragma unroll
      for (int n = 0; n < 4; ++n) {
        const int col = wc * 64 + n * 16 + lr;
        const int slot = (kk * 4 + ls) ^ (col & 7);
        bfr[n] = *(const bf16x8*)(Bs + col * 64 + slot * 8);
      }
#pragma unroll
      for (int m = 0; m < MB; ++m)
#pragma unroll
        for (int n = 0; n < 4; ++n) acc[m][n] = MFMA_BF16(af[m], bfr[n], acc[m][n]);
    }
    __syncthreads();
  }

  if (OUTMODE == 2) {
    const int pn0 = n0 + wc * 64;
#pragma unroll
    for (int m = 0; m < MB; ++m) {
#pragma unroll
      for (int j = 0; j < 2; ++j) {
        const int ocol = (pn0 >> 1) + j * 16 + lr;
        const float ba = bias[ocol];
        const float bg = bias[(N >> 1) + ocol];
#pragma unroll
        for (int r = 0; r < 4; ++r) {
          const int row = m0 + wr * (BM / 2) + m * 16 + ls * 4 + r;
          const float a = acc[m][2 * j][r] + ba;
          const float g = acc[m][2 * j + 1][r] + bg;
          const float gl = 0.5f * g * (1.f + erff(g * 0.70710678118654752f));
          ((unsigned short*)Cout)[(size_t)row * (N >> 1) + ocol] = f2b(a * gl);
        }
      }
    }
    return;
  }
#pragma unroll
  for (int m = 0; m < MB; ++m) {
#pragma unroll
    for (int n = 0; n < 4; ++n) {
      const int col = n0 + wc * 64 + n * 16 + lr;
      float bv = 0.f;
      if (BIAS) bv = bias[col];
#pragma unroll
      for (int r = 0; r < 4; ++r) {
        const int row = m0 + wr * (BM / 2) + m * 16 + ls * 4 + r;
        float v = acc[m][n][r] + bv;
        if (RES) v += res[(size_t)row * N + col];
        if (OUTMODE == 1)
          ((unsigned short*)Cout)[(size_t)row * N + col] = f2b(v);
        else
          ((float*)Cout)[(size_t)row * N + col] = v;
      }
    }
  }
}

// ---------------------------------------------------------------------------
// Flash attention (R14-proven): K AND V in shared LDS double-buffers via
// gll16 (one barrier per 128-kv tile; all VMEM per tile = 8 stage instrs).
// V staged with inverse-swizzled global source + swizzled ds_read (rule #21).
// No-max softmax, ones-MFMA row sum, XCD-bijective swizzle, setprio.
// ---------------------------------------------------------------------------
template <int RELB>
__global__ __launch_bounds__(256) void attn_kernel(const unsigned short* __restrict__ q,
                                                   const unsigned short* __restrict__ k,
                                                   const unsigned short* __restrict__ vt,
                                                   const float* __restrict__ rel,
                                                   unsigned short* __restrict__ outp,
                                                   int ldq, int ldk) {
  const int lin = blockIdx.x + (blockIdx.y << 4) + (blockIdx.z << 8);
  const int xcd = lin & 7, s = lin >> 3;
  const int g = (xcd << 3) + (s >> 4);
  const int qb = s & 15;
  const int h = g & 15, b = g >> 4;
  const int tid = threadIdx.x;
  const int wid = tid >> 6, lane = tid & 63;
  const int lr = lane & 15, ls = lane >> 4;
  const int q0 = (qb << 6) + (wid << 4);
  const float L2E = 1.44269504088896340736f;

  __shared__ unsigned short Ks[2][128 * 64];  // K tile [kv-row][d], slot-swizzled
  __shared__ unsigned short Vs[2][64 * 128];  // V tile [d-row][kv], chunk-swizzled
  __shared__ unsigned short plds[4][16][64];
  __shared__ float tbl[66];

  if (RELB && tid < 65) tbl[tid] = rel[h * 65 + tid] * L2E;

  bf16x8 qa0, qa1;
  {
    const unsigned short* qp = q + (size_t)(b * 1024 + q0 + lr) * ldq + h * 64 + ls * 8;
    const bf16x8 t0 = *(const bf16x8*)qp;
    const bf16x8 t1 = *(const bf16x8*)(qp + 32);
    const float sc = 0.125f * L2E;
#pragma unroll
    for (int j = 0; j < 8; ++j) {
      qa0[j] = (__bf16)((float)t0[j] * sc);
      qa1[j] = (__bf16)((float)t1[j] * sc);
    }
  }
  bf16x8 ones;
#pragma unroll
  for (int j = 0; j < 8; ++j) ones[j] = (__bf16)1.0f;

  const f32x4 fz = {0.f, 0.f, 0.f, 0.f};
  f32x4 oacc[4];
#pragma unroll
  for (int d = 0; d < 4; ++d) oacc[d] = fz;
  f32x4 lacc = fz;

  const unsigned short* kbp = k + (size_t)(b * 1024) * ldk + h * 64;
  const unsigned short* vbp = vt + (size_t)((b * 16 + h) * 64) * 1024;

  // stage K tile: 128 rows x 64 d (4 gll16/thread-block iter)
  auto stageK = [&](int buf, int kv0) {
#pragma unroll
    for (int it = 0; it < 4; ++it) {
      const int u = it * 256 + tid;
      const int row = u >> 3, gs = (u & 7) ^ (row & 7);
      gll16(kbp + (size_t)(kv0 + row) * ldk + gs * 8, Ks[buf] + u * 8);
    }
  };
  // stage V tile: 64 d-rows x 128 kv (16 chunks/row; low-3-bit XOR swizzle)
  auto stageV = [&](int buf, int kv0) {
#pragma unroll
    for (int it = 0; it < 4; ++it) {
      const int u = it * 256 + tid;
      const int row = u >> 4;
      const int ch = u & 15;
      const int gs = (ch & 8) | ((ch & 7) ^ (row & 7));
      gll16(vbp + (size_t)row * 1024 + kv0 + gs * 8, Vs[buf] + u * 8);
    }
  };

  stageK(0, 0);
  stageV(0, 0);
  __syncthreads();

  for (int t = 0; t < 8; ++t) {
    const int kv0 = t << 7;
    if (t + 1 < 8) {
      stageV((t + 1) & 1, kv0 + 128);
      stageK((t + 1) & 1, kv0 + 128);
    }
    const unsigned short* kbuf = Ks[t & 1];
    const unsigned short* vbuf = Vs[t & 1];
#pragma unroll
    for (int sub = 0; sub < 2; ++sub) {
      const int kvs = kv0 + sub * 64;
      f32x4 sc4[4];
      __builtin_amdgcn_s_setprio(1);
#pragma unroll
      for (int nn = 0; nn < 4; ++nn) {
        const int row = sub * 64 + nn * 16 + lr;
        const int s0 = ls ^ (row & 7), s1 = (4 + ls) ^ (row & 7);
        const bf16x8 kb0 = *(const bf16x8*)(kbuf + row * 64 + s0 * 8);
        const bf16x8 kb1 = *(const bf16x8*)(kbuf + row * 64 + s1 * 8);
        f32x4 acc = fz;
        acc = MFMA_BF16(qa0, kb0, acc);
        acc = MFMA_BF16(qa1, kb1, acc);
        sc4[nn] = acc;
      }
      __builtin_amdgcn_s_setprio(0);
      float cb = 0.f;
      bool vary = false;
      if (RELB) {
        if (kvs + 95 <= q0) {
          cb = tbl[64];
        } else if (kvs >= q0 + 47) {
          cb = tbl[0];
        } else {
          vary = true;
        }
      }
      if (vary) {
        const int bd = q0 + ls * 4 - (kvs + lr);
#pragma unroll
        for (int nn = 0; nn < 4; ++nn)
#pragma unroll
          for (int r = 0; r < 4; ++r) {
            int dl = bd + r - nn * 16;
            dl = dl < -32 ? -32 : (dl > 32 ? 32 : dl);
            const float p = __builtin_amdgcn_exp2f(fminf(sc4[nn][r] + tbl[dl + 32], 60.f));
            const int qq = ls * 4 + r;
            const int colw = ((((nn << 1) + (lr >> 3)) ^ (qq & 7)) << 3) + (lr & 7);
            plds[wid][qq][colw] = bcvt(p);
          }
      } else {
#pragma unroll
        for (int nn = 0; nn < 4; ++nn)
#pragma unroll
          for (int r = 0; r < 4; ++r) {
            const float p = __builtin_amdgcn_exp2f(fminf(sc4[nn][r] + cb, 60.f));
            const int qq = ls * 4 + r;
            const int colw = ((((nn << 1) + (lr >> 3)) ^ (qq & 7)) << 3) + (lr & 7);
            plds[wid][qq][colw] = bcvt(p);
          }
      }
      asm volatile("" ::: "memory");
      const bf16x8 pa0 = *(const bf16x8*)&plds[wid][lr][((ls ^ (lr & 7)) << 3)];
      const bf16x8 pa1 = *(const bf16x8*)&plds[wid][lr][(((4 + ls) ^ (lr & 7)) << 3)];
      __builtin_amdgcn_s_setprio(1);
      lacc = MFMA_BF16(pa0, ones, lacc);
      lacc = MFMA_BF16(pa1, ones, lacc);
#pragma unroll
      for (int d = 0; d < 4; ++d) {
        const int rr = d * 16 + lr;
        const int c0 = sub * 8 + ls;
        const int c1 = c0 + 4;
        const int c0s = (c0 & 8) | ((c0 & 7) ^ (rr & 7));
        const int c1s = (c1 & 8) | ((c1 & 7) ^ (rr & 7));
        const bf16x8 vb0 = *(const bf16x8*)(vbuf + rr * 128 + c0s * 8);
        const bf16x8 vb1 = *(const bf16x8*)(vbuf + rr * 128 + c1s * 8);
        oacc[d] = MFMA_BF16(pa0, vb0, oacc[d]);
        oacc[d] = MFMA_BF16(pa1, vb1, oacc[d]);
      }
      __builtin_amdgcn_s_setprio(0);
    }
    __syncthreads();  // buffers (t) free; staged (t+1) visible next iter
  }

  float rinv[4];
#pragma unroll
  for (int r = 0; r < 4; ++r) rinv[r] = 1.0f / lacc[r];
#pragma unroll
  for (int d = 0; d < 4; ++d)
#pragma unroll
    for (int r = 0; r < 4; ++r) {
      const float v = oacc[d][r] * rinv[r];
      outp[(size_t)(b * 1024 + q0 + ls * 4 + r) * 1024 + h * 64 + d * 16 + lr] = bcvt(v);
    }
}

// ---------------------------------------------------------------------------
extern "C" void kernel_launch(void* const* d_in, const int* in_sizes, int n_in,
                              void* d_out, int out_size, void* d_ws, size_t ws_size,
                              hipStream_t stream) {
  (void)in_sizes; (void)n_in; (void)out_size; (void)ws_size;
  const float* hs = (const float*)d_in[0];
  const float* enc = (const float*)d_in[1];
  const float* temb = (const float*)d_in[2];
  const float* wada1 = (const float*)d_in[3];
  const float* bada1 = (const float*)d_in[4];
  const float* wada2 = (const float*)d_in[5];
  const float* bada2 = (const float*)d_in[6];
  const float* wq1 = (const float*)d_in[7];
  const float* wk1 = (const float*)d_in[8];
  const float* wv1 = (const float*)d_in[9];
  const float* wo1 = (const float*)d_in[10];
  const float* bo1 = (const float*)d_in[11];
  const float* rel = (const float*)d_in[12];
  const float* wq2 = (const float*)d_in[13];
  const float* wk2 = (const float*)d_in[14];
  const float* wv2 = (const float*)d_in[15];
  const float* wo2 = (const float*)d_in[16];
  const float* bo2 = (const float*)d_in[17];
  const float* wff1 = (const float*)d_in[18];
  const float* bff1 = (const float*)d_in[19];
  const float* wff2 = (const float*)d_in[20];
  const float* bff2 = (const float*)d_in[21];
  float* out = (float*)d_out;

  char* ws = (char*)d_ws;
  const size_t MB = 1024ull * 1024ull;
  unsigned short* wb_ada = (unsigned short*)(ws + 0 * MB);     // 8MB (ada1|ada2 concat)
  unsigned short* wb_q1 = (unsigned short*)(ws + 8 * MB);      // qkv1 contiguous 6MB
  unsigned short* wb_k1 = (unsigned short*)(ws + 10 * MB);
  unsigned short* wb_v1 = (unsigned short*)(ws + 12 * MB);
  unsigned short* wb_o1 = (unsigned short*)(ws + 14 * MB);
  unsigned short* wb_q2 = (unsigned short*)(ws + 16 * MB);
  unsigned short* wb_k2 = (unsigned short*)(ws + 18 * MB);     // kv2 contiguous 4MB
  unsigned short* wb_v2 = (unsigned short*)(ws + 20 * MB);
  unsigned short* wb_o2 = (unsigned short*)(ws + 22 * MB);
  unsigned short* wb_ff1 = (unsigned short*)(ws + 24 * MB);    // 16MB (permuted)
  unsigned short* wb_ff2 = (unsigned short*)(ws + 40 * MB);    // 8MB
  unsigned short* silu_t = (unsigned short*)(ws + 48 * MB);    // 8MB
  unsigned short* enc_b = (unsigned short*)(ws + 56 * MB);     // 8MB
  unsigned short* ssb = (unsigned short*)(ws + 64 * MB);       // 32MB bf16 (stage 1/2)
  unsigned short* ffin = (unsigned short*)(ws + 64 * MB);      // 32MB (stage 3, aliases ssb)
  float* bias_cat = (float*)(ws + 96 * MB);                    // 16KB (bada1|bada2)
  unsigned short* x1b = (unsigned short*)(ws + 97 * MB);       // 8MB
  unsigned short* qkvb = (unsigned short*)(ws + 105 * MB);     // 24MB (stage 1)
  unsigned short* qb = (unsigned short*)(ws + 105 * MB);       // 8MB (stage 2)
  unsigned short* kvb = (unsigned short*)(ws + 113 * MB);      // 16MB (stage 2)
  unsigned short* vtb = (unsigned short*)(ws + 129 * MB);      // 8MB
  unsigned short* aob = (unsigned short*)(ws + 137 * MB);      // 8MB, ends 145MB

  const int Nrow = 4096;

  // ---- converts (single launch) + bias concat (d2d, graph-safe) ----
  {
    CvtArgs a;
    const float* srcs[12] = {wada1, wada2, wq1, wk1, wv1, wo1, wq2, wk2, wv2, wo2, wff2, enc};
    unsigned short* dsts[12] = {wb_ada, wb_ada + 2048 * 1024, wb_q1, wb_k1, wb_v1, wb_o1,
                                wb_q2, wb_k2, wb_v2, wb_o2, wb_ff2, enc_b};
    const int blks[12] = {2048, 2048, 1024, 1024, 1024, 1024, 1024, 1024, 1024, 1024, 4096, 4096};
    int acc = 0;
    for (int i = 0; i < 12; ++i) { a.src[i] = srcs[i]; a.dst[i] = dsts[i]; a.start[i] = acc; acc += blks[i]; }
    f2b_multi<<<acc, 256, 0, stream>>>(a);
  }
  (void)hipMemcpyAsync(bias_cat, bada1, 2048 * sizeof(float), hipMemcpyDeviceToDevice, stream);
  (void)hipMemcpyAsync(bias_cat + 2048, bada2, 2048 * sizeof(float), hipMemcpyDeviceToDevice, stream);
  f2bperm_kernel<<<8192, 256, 0, stream>>>(wff1, wb_ff1);
  silu_kernel<<<4096, 256, 0, stream>>>(temb, silu_t, 4096 * 1024);

  // ---- batched AdaLN GEMM: ss(4096x4096 bf16) = silu_t @ [wada1|wada2]^T + b ----
  gemm_nt<128, 1, 0, 1><<<dim3(32, 32), 256, 0, stream>>>(silu_t, wb_ada, bias_cat, nullptr, ssb, Nrow, 4096, 1024);

  // ---- stage 1: AdaLN + self-attn + residual ----
  eqln_kernel<1><<<4096, 256, 0, stream>>>(hs, ssb, x1b);
  gemm_nt<128, 0, 0, 1><<<dim3(32, 24), 256, 0, stream>>>(x1b, wb_q1, nullptr, nullptr, qkvb, Nrow, 3072, 1024);
  vtrans_kernel<<<dim3(16, 16, 4), 256, 0, stream>>>(qkvb + 2048, vtb, 1024, 3072);
  attn_kernel<1><<<dim3(16, 16, 4), 256, 0, stream>>>(qkvb, qkvb + 1024, vtb, rel, aob, 3072, 3072);
  gemm_nt<64, 1, 1, 0><<<dim3(64, 8), 256, 0, stream>>>(aob, wb_o1, bo1, hs, out, Nrow, 1024, 1024);

  // ---- stage 2: AdaLN + cross-attn + residual ----
  eqln_kernel<1><<<4096, 256, 0, stream>>>(out, ssb + 2048, x1b);
  gemm_nt<64, 0, 0, 1><<<dim3(64, 8), 256, 0, stream>>>(x1b, wb_q2, nullptr, nullptr, qb, Nrow, 1024, 1024);
  gemm_nt<128, 0, 0, 1><<<dim3(32, 16), 256, 0, stream>>>(enc_b, wb_k2, nullptr, nullptr, kvb, Nrow, 2048, 1024);
  vtrans_kernel<<<dim3(16, 16, 4), 256, 0, stream>>>(kvb + 1024, vtb, 1024, 2048);
  attn_kernel<0><<<dim3(16, 16, 4), 256, 0, stream>>>(qb, kvb, vtb, nullptr, aob, 1024, 2048);
  gemm_nt<64, 1, 1, 0><<<dim3(64, 8), 256, 0, stream>>>(aob, wb_o2, bo2, out, out, Nrow, 1024, 1024);

  // ---- stage 3: eq-LN + fused GEGLU FFN + residual ----
  eqln_kernel<0><<<4096, 256, 0, stream>>>(out, nullptr, x1b);
  gemm_nt<128, 1, 0, 2><<<dim3(32, 64), 256, 0, stream>>>(x1b, wb_ff1, bff1, nullptr, ffin, Nrow, 8192, 1024);
  gemm_nt<64, 1, 1, 0><<<dim3(64, 8), 256, 0, stream>>>(ffin, wb_ff2, bff2, out, out, Nrow, 1024, 4096);
}